// Round 13
// baseline (220.481 us; speedup 1.0000x reference)
//
#include <hip/hip_runtime.h>
#include <stdint.h>

typedef float f32x4 __attribute__((ext_vector_type(4)));
typedef uint32_t u32x4 __attribute__((ext_vector_type(4)));
typedef short s16x8 __attribute__((ext_vector_type(8)));

#define BB   8
#define NN   2048
#define FIN  128
#define FOUT 64

__device__ __forceinline__ uint32_t cvt_pk_bf16(float lo, float hi) {
  uint32_t r;
  asm("v_cvt_pk_bf16_f32 %0, %1, %2" : "=v"(r) : "v"(lo), "v"(hi));
  return r;
}

__device__ __forceinline__ s16x8 mk_s16x8(uint32_t a, uint32_t b, uint32_t c, uint32_t d) {
  union { uint32_t u[4]; s16x8 v; } x;
  x.u[0] = a; x.u[1] = b; x.u[2] = c; x.u[3] = d;
  return x.v;
}

// ---------------------------------------------------------------------------
// Kernel 0 v2 (verbatim R12): adj -> bitmask, lane-major coalesced.
// ---------------------------------------------------------------------------
__global__ void k0_mask(const float* __restrict__ adj, uint32_t* __restrict__ mask) {
  __shared__ uint8_t nib[4][512];
  const int tid  = threadIdx.x;
  const int lane = tid & 63, wid = tid >> 6;
  const int row  = blockIdx.x * 4 + wid;
  const float* base = adj + (size_t)row * NN;

  #pragma unroll
  for (int t = 0; t < 8; ++t) {
    f32x4 v = *(const f32x4*)(base + 256 * t + 4 * lane);
    uint32_t n = (v[0] > 0.f ? 1u : 0u) | (v[1] > 0.f ? 2u : 0u) |
                 (v[2] > 0.f ? 4u : 0u) | (v[3] > 0.f ? 8u : 0u);
    nib[wid][t * 64 + lane] = (uint8_t)n;
  }
  __syncthreads();

  uint64_t x = *(const uint64_t*)(&nib[wid][8 * lane]);
  uint64_t v = (x | (x >> 4))  & 0x00FF00FF00FF00FFull;
  v          = (v | (v >> 8))  & 0x0000FFFF0000FFFFull;
  v          = (v | (v >> 16));
  mask[(size_t)row * 64 + lane] = (uint32_t)v;
}

// ---------------------------------------------------------------------------
// Kernel 1 (verbatim): hidden = h @ W + s1/s2.
// ---------------------------------------------------------------------------
__global__ void k1_hidden(const float* __restrict__ h, const float* __restrict__ W,
                          const float* __restrict__ attw, ushort* __restrict__ hidT,
                          float* __restrict__ s1, float* __restrict__ s2) {
  __shared__ ushort wlds[FOUT * 136];
  const int tid = threadIdx.x;

  for (int idx = tid; idx < FIN * FOUT; idx += 256) {
    int k = idx >> 6, c = idx & 63;
    wlds[c * 136 + k] = (ushort)(cvt_pk_bf16(W[idx], 0.f) & 0xffffu);
  }
  __syncthreads();

  const int bid = ((blockIdx.x & 7) << 5) | (blockIdx.x >> 3);

  const int lane = tid & 63, wid = tid >> 6;
  const int q = lane & 15, g = lane >> 4;
  const int wrow0 = bid * 64 + wid * 16;
  const int b  = wrow0 >> 11;
  const int n0 = wrow0 & (NN - 1);

  const float* hrow = h + (size_t)(wrow0 + q) * FIN + 8 * g;

  f32x4 acc[4];
  #pragma unroll
  for (int nt = 0; nt < 4; ++nt) acc[nt] = {0.f, 0.f, 0.f, 0.f};

  #pragma unroll
  for (int kk = 0; kk < 4; ++kk) {
    f32x4 h0 = *(const f32x4*)(hrow + 32 * kk);
    f32x4 h1 = *(const f32x4*)(hrow + 32 * kk + 4);
    s16x8 A = mk_s16x8(cvt_pk_bf16(h0[0], h0[1]), cvt_pk_bf16(h0[2], h0[3]),
                       cvt_pk_bf16(h1[0], h1[1]), cvt_pk_bf16(h1[2], h1[3]));
    #pragma unroll
    for (int nt = 0; nt < 4; ++nt) {
      s16x8 Bf = *(const s16x8*)(&wlds[(nt * 16 + q) * 136 + 32 * kk + 8 * g]);
      acc[nt] = __builtin_amdgcn_mfma_f32_16x16x32_bf16(A, Bf, acc[nt], 0, 0, 0);
    }
  }

  float a1v[4], a2v[4];
  #pragma unroll
  for (int nt = 0; nt < 4; ++nt) {
    a1v[nt] = attw[nt * 16 + q];
    a2v[nt] = attw[64 + nt * 16 + q];
  }
  float p1[4], p2[4];
  #pragma unroll
  for (int r = 0; r < 4; ++r) {
    float v1 = 0.f, v2 = 0.f;
    #pragma unroll
    for (int nt = 0; nt < 4; ++nt) { v1 += acc[nt][r] * a1v[nt]; v2 += acc[nt][r] * a2v[nt]; }
    #pragma unroll
    for (int m = 1; m < 16; m <<= 1) { v1 += __shfl_xor(v1, m, 64); v2 += __shfl_xor(v2, m, 64); }
    p1[r] = v1; p2[r] = v2;
  }
  if (q < 4) {
    int gr = wrow0 + 4 * g + q;
    float v1 = (q == 0) ? p1[0] : (q == 1) ? p1[1] : (q == 2) ? p1[2] : p1[3];
    float v2 = (q == 0) ? p2[0] : (q == 1) ? p2[1] : (q == 2) ? p2[2] : p2[3];
    s1[gr] = v1; s2[gr] = v2;
  }

  #pragma unroll
  for (int nt = 0; nt < 4; ++nt) {
    uint32_t lo = cvt_pk_bf16(acc[nt][0], acc[nt][1]);
    uint32_t hi = cvt_pk_bf16(acc[nt][2], acc[nt][3]);
    *(uint2*)(hidT + ((size_t)b * FOUT + nt * 16 + q) * NN + n0 + 4 * g) = make_uint2(lo, hi);
  }
}

// ---------------------------------------------------------------------------
// Kernel 2 (verbatim R11/R12, passing): mask-driven softmax + PV.
// ---------------------------------------------------------------------------
__global__ void k2_attn(
    const uint32_t* __restrict__ mask, const ushort* __restrict__ hidT,
    const float* __restrict__ s1, const float* __restrict__ s2,
    float* __restrict__ out) {
  __shared__ float s2l[NN];
  __shared__ float part[4][16][64];
  __shared__ float partl[4][16];

  const int tid = threadIdx.x;
  const int bid = ((blockIdx.x & 7) << 7) | (blockIdx.x >> 3);
  const int b  = bid >> 7;
  const int i0 = (bid & 127) << 4;

  {
    const f32x4* src = (const f32x4*)(s2 + b * NN);
    f32x4* dst = (f32x4*)s2l;
    #pragma unroll
    for (int it = 0; it < 2; ++it) dst[tid + 256 * it] = src[tid + 256 * it];
  }
  __syncthreads();

  const int lane = tid & 63, wid = tid >> 6;
  const int q = lane & 15, g = lane >> 4;
  const float s1r = s1[b * NN + i0 + q];

  const uint32_t* mrow = mask + (size_t)(b * NN + i0 + q) * 64 + wid * 16;
  const ushort*   hq   = hidT + ((size_t)b * FOUT + q) * NN;

  f32x4 acc0 = {0,0,0,0}, acc1 = {0,0,0,0}, acc2 = {0,0,0,0}, acc3 = {0,0,0,0};
  float lsum = 0.f;

  const int jbase = wid * 512 + 8 * g;
  const int gsh = g << 3;

  #pragma unroll
  for (int s = 0; s < 16; ++s) {
    const int j0 = jbase + 32 * s;
    const uint32_t mb = (mrow[s] >> gsh) & 0xffu;
    f32x4 ct0 = *(const f32x4*)(s2l + j0);
    f32x4 ct1 = *(const f32x4*)(s2l + j0 + 4);
    u32x4 cb0 = *(const u32x4*)(hq + (size_t)0 * 16 * NN + j0);
    u32x4 cb1 = *(const u32x4*)(hq + (size_t)1 * 16 * NN + j0);
    u32x4 cb2 = *(const u32x4*)(hq + (size_t)2 * 16 * NN + j0);
    u32x4 cb3 = *(const u32x4*)(hq + (size_t)3 * 16 * NN + j0);

    float e0 = s1r + ct0[0], e1 = s1r + ct0[1], e2 = s1r + ct0[2], e3 = s1r + ct0[3];
    float e4 = s1r + ct1[0], e5 = s1r + ct1[1], e6 = s1r + ct1[2], e7 = s1r + ct1[3];
    float p0 = (mb &   1u) ? __expf(fmaxf(e0, 0.2f * e0)) : 0.f;
    float p1 = (mb &   2u) ? __expf(fmaxf(e1, 0.2f * e1)) : 0.f;
    float p2 = (mb &   4u) ? __expf(fmaxf(e2, 0.2f * e2)) : 0.f;
    float p3 = (mb &   8u) ? __expf(fmaxf(e3, 0.2f * e3)) : 0.f;
    float p4 = (mb &  16u) ? __expf(fmaxf(e4, 0.2f * e4)) : 0.f;
    float p5 = (mb &  32u) ? __expf(fmaxf(e5, 0.2f * e5)) : 0.f;
    float p6 = (mb &  64u) ? __expf(fmaxf(e6, 0.2f * e6)) : 0.f;
    float p7 = (mb & 128u) ? __expf(fmaxf(e7, 0.2f * e7)) : 0.f;
    lsum += ((p0 + p1) + (p2 + p3)) + ((p4 + p5) + (p6 + p7));

    s16x8 A = mk_s16x8(cvt_pk_bf16(p0, p1), cvt_pk_bf16(p2, p3),
                       cvt_pk_bf16(p4, p5), cvt_pk_bf16(p6, p7));
    union { u32x4 u; s16x8 v; } w0, w1, w2, w3;
    w0.u = cb0; w1.u = cb1; w2.u = cb2; w3.u = cb3;
    acc0 = __builtin_amdgcn_mfma_f32_16x16x32_bf16(A, w0.v, acc0, 0, 0, 0);
    acc1 = __builtin_amdgcn_mfma_f32_16x16x32_bf16(A, w1.v, acc1, 0, 0, 0);
    acc2 = __builtin_amdgcn_mfma_f32_16x16x32_bf16(A, w2.v, acc2, 0, 0, 0);
    acc3 = __builtin_amdgcn_mfma_f32_16x16x32_bf16(A, w3.v, acc3, 0, 0, 0);
  }

  lsum += __shfl_xor(lsum, 16, 64);
  lsum += __shfl_xor(lsum, 32, 64);
  if (lane < 16) partl[wid][lane] = lsum;

  #pragma unroll
  for (int r = 0; r < 4; ++r) {
    part[wid][4 * g + r][ 0 + q] = acc0[r];
    part[wid][4 * g + r][16 + q] = acc1[r];
    part[wid][4 * g + r][32 + q] = acc2[r];
    part[wid][4 * g + r][48 + q] = acc3[r];
  }
  __syncthreads();

  #pragma unroll
  for (int q4 = 0; q4 < 4; ++q4) {
    int idx = tid + 256 * q4;
    int row = idx >> 6, col = idx & 63;
    float v  = (part[0][row][col] + part[1][row][col]) +
               (part[2][row][col] + part[3][row][col]);
    float li = (partl[0][row] + partl[1][row]) + (partl[2][row] + partl[3][row]);
    float hp = v / li;
    out[(size_t)(b * NN + i0 + row) * 64 + col] = (hp > 0.f) ? hp : expm1f(hp);
  }
}

// ---------------------------------------------------------------------------
// PROBE H (diagnostic, grid 4096 = 4x replication of k2's hidT+MFMA path).
// 40KB LDS pad to match k2's 4-blocks/CU occupancy. Writes to ws scratch.
// ---------------------------------------------------------------------------
__global__ void probe_h(const ushort* __restrict__ hidT, float* __restrict__ dst) {
  __shared__ float pad[10240];   // 40 KB
  const int tid = threadIdx.x;
  const int pb  = blockIdx.x & 1023;
  const int bid = ((pb & 7) << 7) | (pb >> 3);
  const int b   = bid >> 7;

  const int lane = tid & 63, wid = tid >> 6;
  const int q = lane & 15, g = lane >> 4;
  const ushort* hq = hidT + ((size_t)b * FOUT + q) * NN;

  f32x4 acc0 = {0,0,0,0}, acc1 = {0,0,0,0}, acc2 = {0,0,0,0}, acc3 = {0,0,0,0};
  const int jbase = wid * 512 + 8 * g;
  const s16x8 A = mk_s16x8(0x3f803f80u, 0x3f803f80u, 0x3f803f80u, 0x3f803f80u);

  #pragma unroll
  for (int s = 0; s < 16; ++s) {
    const int j0 = jbase + 32 * s;
    u32x4 cb0 = *(const u32x4*)(hq + (size_t)0 * 16 * NN + j0);
    u32x4 cb1 = *(const u32x4*)(hq + (size_t)1 * 16 * NN + j0);
    u32x4 cb2 = *(const u32x4*)(hq + (size_t)2 * 16 * NN + j0);
    u32x4 cb3 = *(const u32x4*)(hq + (size_t)3 * 16 * NN + j0);
    union { u32x4 u; s16x8 v; } w0, w1, w2, w3;
    w0.u = cb0; w1.u = cb1; w2.u = cb2; w3.u = cb3;
    acc0 = __builtin_amdgcn_mfma_f32_16x16x32_bf16(A, w0.v, acc0, 0, 0, 0);
    acc1 = __builtin_amdgcn_mfma_f32_16x16x32_bf16(A, w1.v, acc1, 0, 0, 0);
    acc2 = __builtin_amdgcn_mfma_f32_16x16x32_bf16(A, w2.v, acc2, 0, 0, 0);
    acc3 = __builtin_amdgcn_mfma_f32_16x16x32_bf16(A, w3.v, acc3, 0, 0, 0);
  }

  pad[tid] = acc0[0] + acc1[1] + acc2[2] + acc3[3];
  __syncthreads();
  dst[(size_t)blockIdx.x * 256 + tid] = pad[tid] + pad[tid ^ 1] + pad[(tid + 999) & 255];
}

// ---------------------------------------------------------------------------
// PROBE E (diagnostic, grid 4096 = 4x replication of k2's mask+s2l+exp path).
// 40KB LDS total; cvt_pk results kept alive via asm. Writes to ws scratch.
// ---------------------------------------------------------------------------
__global__ void probe_e(const uint32_t* __restrict__ mask, const float* __restrict__ s1,
                        const float* __restrict__ s2, float* __restrict__ dst) {
  __shared__ float s2l[NN];
  __shared__ float pad[8192];    // 8 + 32 = 40 KB
  const int tid = threadIdx.x;
  const int pb  = blockIdx.x & 1023;
  const int bid = ((pb & 7) << 7) | (pb >> 3);
  const int b   = bid >> 7;
  const int i0  = (bid & 127) << 4;

  {
    const f32x4* src = (const f32x4*)(s2 + b * NN);
    f32x4* dstl = (f32x4*)s2l;
    #pragma unroll
    for (int it = 0; it < 2; ++it) dstl[tid + 256 * it] = src[tid + 256 * it];
  }
  __syncthreads();

  const int lane = tid & 63, wid = tid >> 6;
  const int q = lane & 15, g = lane >> 4;
  const float s1r = s1[b * NN + i0 + q];
  const uint32_t* mrow = mask + (size_t)(b * NN + i0 + q) * 64 + wid * 16;

  float lsum = 0.f;
  const int jbase = wid * 512 + 8 * g;
  const int gsh = g << 3;

  #pragma unroll
  for (int s = 0; s < 16; ++s) {
    const int j0 = jbase + 32 * s;
    const uint32_t mb = (mrow[s] >> gsh) & 0xffu;
    f32x4 ct0 = *(const f32x4*)(s2l + j0);
    f32x4 ct1 = *(const f32x4*)(s2l + j0 + 4);

    float e0 = s1r + ct0[0], e1 = s1r + ct0[1], e2 = s1r + ct0[2], e3 = s1r + ct0[3];
    float e4 = s1r + ct1[0], e5 = s1r + ct1[1], e6 = s1r + ct1[2], e7 = s1r + ct1[3];
    float p0 = (mb &   1u) ? __expf(fmaxf(e0, 0.2f * e0)) : 0.f;
    float p1 = (mb &   2u) ? __expf(fmaxf(e1, 0.2f * e1)) : 0.f;
    float p2 = (mb &   4u) ? __expf(fmaxf(e2, 0.2f * e2)) : 0.f;
    float p3 = (mb &   8u) ? __expf(fmaxf(e3, 0.2f * e3)) : 0.f;
    float p4 = (mb &  16u) ? __expf(fmaxf(e4, 0.2f * e4)) : 0.f;
    float p5 = (mb &  32u) ? __expf(fmaxf(e5, 0.2f * e5)) : 0.f;
    float p6 = (mb &  64u) ? __expf(fmaxf(e6, 0.2f * e6)) : 0.f;
    float p7 = (mb & 128u) ? __expf(fmaxf(e7, 0.2f * e7)) : 0.f;
    lsum += ((p0 + p1) + (p2 + p3)) + ((p4 + p5) + (p6 + p7));

    uint32_t a0 = cvt_pk_bf16(p0, p1), a1 = cvt_pk_bf16(p2, p3);
    uint32_t a2 = cvt_pk_bf16(p4, p5), a3 = cvt_pk_bf16(p6, p7);
    asm volatile("" : : "v"(a0), "v"(a1), "v"(a2), "v"(a3));
  }

  pad[tid] = lsum;
  __syncthreads();
  dst[(size_t)blockIdx.x * 256 + tid] = pad[tid] + pad[tid ^ 1];
}

extern "C" void kernel_launch(void* const* d_in, const int* in_sizes, int n_in,
                              void* d_out, int out_size, void* d_ws, size_t ws_size,
                              hipStream_t stream) {
  const float* h    = (const float*)d_in[0];
  const float* adj  = (const float*)d_in[1];
  const float* W    = (const float*)d_in[2];
  const float* attw = (const float*)d_in[3];
  float* out = (float*)d_out;

  char* ws = (char*)d_ws;
  ushort*   hidT = (ushort*)ws;                                 // 2 MB
  float*    s1   = (float*)(ws + (2u << 20));                   // 64 KB
  float*    s2   = (float*)(ws + (2u << 20) + (64u << 10));     // 64 KB
  uint32_t* mask = (uint32_t*)(ws + (4u << 20));                // 4 MB
  float*    dstH = (float*)(ws + (64u << 20));                  // 4 MB scratch
  float*    dstE = (float*)(ws + (96u << 20));                  // 4 MB scratch

  hipLaunchKernelGGL(k0_mask, dim3(4096), dim3(256), 0, stream, adj, mask);
  hipLaunchKernelGGL(k1_hidden, dim3(256), dim3(256), 0, stream, h, W, attw, hidT, s1, s2);
  hipLaunchKernelGGL(k2_attn, dim3(BB * (NN / 16)), dim3(256), 0, stream, mask, hidT, s1, s2, out);

  // --- diagnostic probes (write to ws scratch; 4x replication each) ---
  hipLaunchKernelGGL(probe_h, dim3(4096), dim3(256), 0, stream, hidT, dstH);
  hipLaunchKernelGGL(probe_e, dim3(4096), dim3(256), 0, stream, mask, s1, s2, dstE);
}

// Round 14
// 59.297 us; speedup vs baseline: 3.7182x; 3.7182x over previous
//
#include <hip/hip_runtime.h>
#include <stdint.h>

typedef float f32x4 __attribute__((ext_vector_type(4)));
typedef uint32_t u32x4 __attribute__((ext_vector_type(4)));
typedef short s16x8 __attribute__((ext_vector_type(8)));

#define BB   8
#define NN   2048
#define FIN  128
#define FOUT 64

__device__ __forceinline__ uint32_t cvt_pk_bf16(float lo, float hi) {
  uint32_t r;
  asm("v_cvt_pk_bf16_f32 %0, %1, %2" : "=v"(r) : "v"(lo), "v"(hi));
  return r;
}

__device__ __forceinline__ s16x8 mk_s16x8(uint32_t a, uint32_t b, uint32_t c, uint32_t d) {
  union { uint32_t u[4]; s16x8 v; } x;
  x.u[0] = a; x.u[1] = b; x.u[2] = c; x.u[3] = d;
  return x.v;
}

// ---------------------------------------------------------------------------
// k01: fused. ALL 4096 blocks: adj->bitmask slice (4 rows each, coalesced).
// Blocks < 256 additionally run the k1 hidden/s1/s2 body (R1 lineage,
// known-good) -- its ~6us hides under the 21us adj stream.
// ---------------------------------------------------------------------------
__global__ void k01(const float* __restrict__ adj, uint32_t* __restrict__ mask,
                    const float* __restrict__ h, const float* __restrict__ W,
                    const float* __restrict__ attw, ushort* __restrict__ hidT,
                    float* __restrict__ s1, float* __restrict__ s2) {
  __shared__ uint8_t nib[4][512];
  __shared__ ushort wlds[FOUT * 136];

  const int tid  = threadIdx.x;
  const int lane = tid & 63, wid = tid >> 6;

  // ---- mask slice (all blocks) ----
  {
    const int row = blockIdx.x * 4 + wid;
    const float* base = adj + (size_t)row * NN;
    #pragma unroll
    for (int t = 0; t < 8; ++t) {
      f32x4 v = *(const f32x4*)(base + 256 * t + 4 * lane);
      uint32_t n = (v[0] > 0.f ? 1u : 0u) | (v[1] > 0.f ? 2u : 0u) |
                   (v[2] > 0.f ? 4u : 0u) | (v[3] > 0.f ? 8u : 0u);
      nib[wid][t * 64 + lane] = (uint8_t)n;
    }
    __syncthreads();
    uint64_t x = *(const uint64_t*)(&nib[wid][8 * lane]);
    uint64_t v = (x | (x >> 4))  & 0x00FF00FF00FF00FFull;
    v          = (v | (v >> 8))  & 0x0000FFFF0000FFFFull;
    v          = (v | (v >> 16));
    mask[(size_t)row * 64 + lane] = (uint32_t)v;
  }

  // ---- k1 body (blocks < 256 only) ----
  if (blockIdx.x < 256) {
    for (int idx = tid; idx < FIN * FOUT; idx += 256) {
      int k = idx >> 6, c = idx & 63;
      wlds[c * 136 + k] = (ushort)(cvt_pk_bf16(W[idx], 0.f) & 0xffffu);
    }
    __syncthreads();

    const int bid = ((blockIdx.x & 7) << 5) | (blockIdx.x >> 3);
    const int q = lane & 15, g = lane >> 4;
    const int wrow0 = bid * 64 + wid * 16;
    const int b  = wrow0 >> 11;
    const int n0 = wrow0 & (NN - 1);

    const float* hrow = h + (size_t)(wrow0 + q) * FIN + 8 * g;

    f32x4 acc[4];
    #pragma unroll
    for (int nt = 0; nt < 4; ++nt) acc[nt] = {0.f, 0.f, 0.f, 0.f};

    #pragma unroll
    for (int kk = 0; kk < 4; ++kk) {
      f32x4 h0 = *(const f32x4*)(hrow + 32 * kk);
      f32x4 h1 = *(const f32x4*)(hrow + 32 * kk + 4);
      s16x8 A = mk_s16x8(cvt_pk_bf16(h0[0], h0[1]), cvt_pk_bf16(h0[2], h0[3]),
                         cvt_pk_bf16(h1[0], h1[1]), cvt_pk_bf16(h1[2], h1[3]));
      #pragma unroll
      for (int nt = 0; nt < 4; ++nt) {
        s16x8 Bf = *(const s16x8*)(&wlds[(nt * 16 + q) * 136 + 32 * kk + 8 * g]);
        acc[nt] = __builtin_amdgcn_mfma_f32_16x16x32_bf16(A, Bf, acc[nt], 0, 0, 0);
      }
    }

    float a1v[4], a2v[4];
    #pragma unroll
    for (int nt = 0; nt < 4; ++nt) {
      a1v[nt] = attw[nt * 16 + q];
      a2v[nt] = attw[64 + nt * 16 + q];
    }
    float p1[4], p2[4];
    #pragma unroll
    for (int r = 0; r < 4; ++r) {
      float v1 = 0.f, v2 = 0.f;
      #pragma unroll
      for (int nt = 0; nt < 4; ++nt) { v1 += acc[nt][r] * a1v[nt]; v2 += acc[nt][r] * a2v[nt]; }
      #pragma unroll
      for (int m = 1; m < 16; m <<= 1) { v1 += __shfl_xor(v1, m, 64); v2 += __shfl_xor(v2, m, 64); }
      p1[r] = v1; p2[r] = v2;
    }
    if (q < 4) {
      int gr = wrow0 + 4 * g + q;
      float v1 = (q == 0) ? p1[0] : (q == 1) ? p1[1] : (q == 2) ? p1[2] : p1[3];
      float v2 = (q == 0) ? p2[0] : (q == 1) ? p2[1] : (q == 2) ? p2[2] : p2[3];
      s1[gr] = v1; s2[gr] = v2;
    }

    #pragma unroll
    for (int nt = 0; nt < 4; ++nt) {
      uint32_t lo = cvt_pk_bf16(acc[nt][0], acc[nt][1]);
      uint32_t hi = cvt_pk_bf16(acc[nt][2], acc[nt][3]);
      *(uint2*)(hidT + ((size_t)b * FOUT + nt * 16 + q) * NN + n0 + 4 * g) = make_uint2(lo, hi);
    }
  }
}

// ---------------------------------------------------------------------------
// k2 v5 (GEMM-style): grid 1024 x 512 thr. Block = 64 i-rows x 512-j window.
// 4 chunks of 128 j; hidden chunk (64f x 128j bf16 = 16KB) staged in LDS with
// XOR swizzle, shared by all 8 waves (4 row-groups x 2 j-halves).
// Writes unnormalized 64x64 partial + 64 lsums to ws; k3 combines.
// ---------------------------------------------------------------------------
__global__ void k2_attn(
    const uint32_t* __restrict__ mask, const ushort* __restrict__ hidT,
    const float* __restrict__ s1, const float* __restrict__ s2,
    float* __restrict__ parts) {
  __shared__ __align__(16) char Hb[16384];
  __shared__ float s2l[512];
  __shared__ float part[4][16][64];
  __shared__ float partl[4][16];

  const int tid = threadIdx.x;
  // XCD swizzle: 1024 blocks, XCD x <- batch x
  const int sb  = ((blockIdx.x & 7) << 7) | (blockIdx.x >> 3);
  const int b   = sb >> 7;
  const int rem = sb & 127;
  const int ib  = rem >> 2;           // i-block 0..31
  const int jq  = rem & 3;            // j-window 0..3
  const int i0  = ib << 6;
  const int jbase = jq << 9;          // 512-j window start

  if (tid < 512) s2l[tid] = s2[b * NN + jbase + tid];

  const int lane = tid & 63, wid = tid >> 6;
  const int q = lane & 15, g = lane >> 4;
  const int r16 = wid & 3;            // row-group
  const int jp  = wid >> 2;           // j-half within chunk
  const int row = i0 + r16 * 16 + q;
  const float s1r = s1[b * NN + row];
  const uint32_t* mrow = mask + (size_t)(b * NN + row) * 64 + jq * 16 + jp * 2;

  const ushort* hsrc = hidT + (size_t)b * FOUT * NN + jbase;
  const int sf = tid >> 4;            // staging f-row 0..31 (+32 for round 2)
  const int jslot = tid & 15;         // staging 16B slot
  const int swz = (q & 7) << 4;
  const int gsh = g << 3;

  f32x4 acc0 = {0,0,0,0}, acc1 = {0,0,0,0}, acc2 = {0,0,0,0}, acc3 = {0,0,0,0};
  float lsum = 0.f;

  #pragma unroll
  for (int c = 0; c < 4; ++c) {
    __syncthreads();                   // previous chunk's reads done
    #pragma unroll
    for (int rd = 0; rd < 2; ++rd) {
      const int f = sf + 32 * rd;
      u32x4 v = *(const u32x4*)(hsrc + (size_t)f * NN + c * 128 + jslot * 8);
      *(u32x4*)(Hb + (f << 8) + (((jslot << 4)) ^ ((f & 7) << 4))) = v;
    }
    __syncthreads();                   // chunk staged

    #pragma unroll
    for (int s = 0; s < 2; ++s) {
      const int jl = jp * 64 + s * 32 + 8 * g;     // chunk-local 0..127
      const uint32_t mb = (mrow[c * 4 + s] >> gsh) & 0xffu;
      f32x4 ct0 = *(const f32x4*)(s2l + c * 128 + jl);
      f32x4 ct1 = *(const f32x4*)(s2l + c * 128 + jl + 4);
      const int jb = (jl << 1);                    // byte in 256B row
      u32x4 cb0 = *(const u32x4*)(Hb + (((0 * 16 + q) << 8) + (jb ^ swz)));
      u32x4 cb1 = *(const u32x4*)(Hb + (((1 * 16 + q) << 8) + (jb ^ swz)));
      u32x4 cb2 = *(const u32x4*)(Hb + (((2 * 16 + q) << 8) + (jb ^ swz)));
      u32x4 cb3 = *(const u32x4*)(Hb + (((3 * 16 + q) << 8) + (jb ^ swz)));

      float e0 = s1r + ct0[0], e1 = s1r + ct0[1], e2 = s1r + ct0[2], e3 = s1r + ct0[3];
      float e4 = s1r + ct1[0], e5 = s1r + ct1[1], e6 = s1r + ct1[2], e7 = s1r + ct1[3];
      float p0 = (mb &   1u) ? __expf(fmaxf(e0, 0.2f * e0)) : 0.f;
      float p1 = (mb &   2u) ? __expf(fmaxf(e1, 0.2f * e1)) : 0.f;
      float p2 = (mb &   4u) ? __expf(fmaxf(e2, 0.2f * e2)) : 0.f;
      float p3 = (mb &   8u) ? __expf(fmaxf(e3, 0.2f * e3)) : 0.f;
      float p4 = (mb &  16u) ? __expf(fmaxf(e4, 0.2f * e4)) : 0.f;
      float p5 = (mb &  32u) ? __expf(fmaxf(e5, 0.2f * e5)) : 0.f;
      float p6 = (mb &  64u) ? __expf(fmaxf(e6, 0.2f * e6)) : 0.f;
      float p7 = (mb & 128u) ? __expf(fmaxf(e7, 0.2f * e7)) : 0.f;
      lsum += ((p0 + p1) + (p2 + p3)) + ((p4 + p5) + (p6 + p7));

      s16x8 A = mk_s16x8(cvt_pk_bf16(p0, p1), cvt_pk_bf16(p2, p3),
                         cvt_pk_bf16(p4, p5), cvt_pk_bf16(p6, p7));
      union { u32x4 u; s16x8 v; } w0, w1, w2, w3;
      w0.u = cb0; w1.u = cb1; w2.u = cb2; w3.u = cb3;
      acc0 = __builtin_amdgcn_mfma_f32_16x16x32_bf16(A, w0.v, acc0, 0, 0, 0);
      acc1 = __builtin_amdgcn_mfma_f32_16x16x32_bf16(A, w1.v, acc1, 0, 0, 0);
      acc2 = __builtin_amdgcn_mfma_f32_16x16x32_bf16(A, w2.v, acc2, 0, 0, 0);
      acc3 = __builtin_amdgcn_mfma_f32_16x16x32_bf16(A, w3.v, acc3, 0, 0, 0);
    }
  }

  // reduce lsum over g-groups -> all lanes hold row-q sum (this wave's j-part)
  lsum += __shfl_xor(lsum, 16, 64);
  lsum += __shfl_xor(lsum, 32, 64);

  // combine j-half pairs (wid and wid+4 share rows)
  if (wid >= 4) {
    if (lane < 16) partl[wid - 4][lane] = lsum;
    #pragma unroll
    for (int r = 0; r < 4; ++r) {
      part[wid - 4][4 * g + r][ 0 + q] = acc0[r];
      part[wid - 4][4 * g + r][16 + q] = acc1[r];
      part[wid - 4][4 * g + r][32 + q] = acc2[r];
      part[wid - 4][4 * g + r][48 + q] = acc3[r];
    }
  }
  __syncthreads();
  if (wid < 4) {
    lsum += partl[wid][q];
    #pragma unroll
    for (int r = 0; r < 4; ++r) {
      acc0[r] += part[wid][4 * g + r][ 0 + q];
      acc1[r] += part[wid][4 * g + r][16 + q];
      acc2[r] += part[wid][4 * g + r][32 + q];
      acc3[r] += part[wid][4 * g + r][48 + q];
    }
    float* po = parts + ((size_t)(b * 32 + ib) * 4 + jq) * 4160;
    #pragma unroll
    for (int r = 0; r < 4; ++r) {
      po[(r16 * 16 + 4 * g + r) * 64 +  0 + q] = acc0[r];
      po[(r16 * 16 + 4 * g + r) * 64 + 16 + q] = acc1[r];
      po[(r16 * 16 + 4 * g + r) * 64 + 32 + q] = acc2[r];
      po[(r16 * 16 + 4 * g + r) * 64 + 48 + q] = acc3[r];
    }
    if (lane < 16) po[4096 + r16 * 16 + q] = lsum;
  }
}

// ---------------------------------------------------------------------------
// k3: combine 4 j-window partials, normalize, ELU, write out.
// grid 256 x 256 thr; one 64x64 i-tile per block.
// ---------------------------------------------------------------------------
__global__ void k3_combine(const float* __restrict__ parts, float* __restrict__ out) {
  __shared__ float lrow[64];
  const int tid = threadIdx.x;
  const int sb  = ((blockIdx.x & 7) << 5) | (blockIdx.x >> 3);
  const int b   = sb >> 5;
  const int ib  = sb & 31;
  const float* p0 = parts + (size_t)(b * 32 + ib) * 4 * 4160;

  if (tid < 64)
    lrow[tid] = (p0[4096 + tid] + p0[4160 + 4096 + tid]) +
                (p0[8320 + 4096 + tid] + p0[12480 + 4096 + tid]);
  __syncthreads();

  #pragma unroll
  for (int k = 0; k < 16; ++k) {
    const int idx = k * 256 + tid;
    const int row = idx >> 6, col = idx & 63;
    float v = (p0[idx] + p0[4160 + idx]) + (p0[8320 + idx] + p0[12480 + idx]);
    float hp = v / lrow[row];
    out[(size_t)(b * NN + ib * 64 + row) * 64 + col] = (hp > 0.f) ? hp : expm1f(hp);
  }
}

extern "C" void kernel_launch(void* const* d_in, const int* in_sizes, int n_in,
                              void* d_out, int out_size, void* d_ws, size_t ws_size,
                              hipStream_t stream) {
  const float* h    = (const float*)d_in[0];
  const float* adj  = (const float*)d_in[1];
  const float* W    = (const float*)d_in[2];
  const float* attw = (const float*)d_in[3];
  float* out = (float*)d_out;

  char* ws = (char*)d_ws;
  ushort*   hidT  = (ushort*)ws;                                // 2 MB
  float*    s1    = (float*)(ws + (2u << 20));                  // 64 KB
  float*    s2    = (float*)(ws + (2u << 20) + (64u << 10));    // 64 KB
  uint32_t* mask  = (uint32_t*)(ws + (4u << 20));               // 4 MB
  float*    parts = (float*)(ws + (8u << 20));                  // 17 MB

  hipLaunchKernelGGL(k01, dim3(4096), dim3(256), 0, stream,
                     adj, mask, h, W, attw, hidT, s1, s2);
  hipLaunchKernelGGL(k2_attn, dim3(1024), dim3(512), 0, stream,
                     mask, hidT, s1, s2, parts);
  hipLaunchKernelGGL(k3_combine, dim3(256), dim3(256), 0, stream, parts, out);
}